// Round 14
// baseline (125.496 us; speedup 1.0000x reference)
//
#include <hip/hip_runtime.h>

typedef __bf16 bf16x8 __attribute__((ext_vector_type(8)));
typedef float f32x4 __attribute__((ext_vector_type(4)));
typedef unsigned short u16x4 __attribute__((ext_vector_type(4)));
typedef unsigned int u32x4 __attribute__((ext_vector_type(4)));

#define LDA 72    // bf16 row pitch (144 B): 16B-aligned rows

__device__ __forceinline__ unsigned short f2bf(float f) {
  __bf16 b = (__bf16)f;                      // hardware RTNE v_cvt
  return __builtin_bit_cast(unsigned short, b);
}

__device__ __forceinline__ u16x4 pack4(f32x4 v) {
  u16x4 r;
  r[0] = f2bf(v[0]); r[1] = f2bf(v[1]); r[2] = f2bf(v[2]); r[3] = f2bf(v[3]);
  return r;
}

__device__ __forceinline__ bf16x8 frag8(const unsigned short* p) {
  typedef unsigned short u16x8v __attribute__((ext_vector_type(8)));
  return __builtin_bit_cast(bf16x8, *reinterpret_cast<const u16x8v*>(p));
}

#define MFMA(a, b, c) __builtin_amdgcn_mfma_f32_16x16x32_bf16(a, b, c, 0, 0, 0)

// ---------------------------------------------------------------------------
// In-register C-frag -> A/B-frag conversion (validated permlane butterfly).
// ---------------------------------------------------------------------------
__device__ __forceinline__ void cfrag2bfrag(const f32x4 v[4], bf16x8 out[2]) {
  unsigned O[4][2];
  #pragma unroll
  for (int si = 0; si < 4; ++si) {
    u16x4 p = pack4(v[si]);
    O[si][0] = (unsigned)p[0] | ((unsigned)p[1] << 16);
    O[si][1] = (unsigned)p[2] | ((unsigned)p[3] << 16);
  }
  unsigned H[2][2][2];
  #pragma unroll
  for (int s1 = 0; s1 < 2; ++s1)
    #pragma unroll
    for (int d = 0; d < 2; ++d) {
      auto r = __builtin_amdgcn_permlane32_swap(O[2 * s1][d], O[2 * s1 + 1][d], false, false);
      H[s1][0][d] = r[0];
      H[s1][1][d] = r[1];
    }
  #pragma unroll
  for (int e1 = 0; e1 < 2; ++e1) {
    auto r0 = __builtin_amdgcn_permlane16_swap(H[e1][0][0], H[e1][1][0], false, false);
    auto r1 = __builtin_amdgcn_permlane16_swap(H[e1][0][1], H[e1][1][1], false, false);
    u32x4 f;
    f[0] = r0[0]; f[1] = r1[0]; f[2] = r0[1]; f[3] = r1[1];
    out[e1] = __builtin_bit_cast(bf16x8, f);
  }
}

// ---------------------------------------------------------------------------
// Fuse + pack (unchanged): t=0: M_h = Wq Wk^T * 0.125*log2e; t=1: N_h = Wv Wp_h.
// ---------------------------------------------------------------------------
__global__ __launch_bounds__(256) void fuse_pack(
    const float* __restrict__ Wq, const float* __restrict__ Wk,
    const float* __restrict__ Wv, const float* __restrict__ Wp,
    unsigned short* __restrict__ wf) {
  __shared__ float A[64 * 65];
  __shared__ float B[64 * 65];
  const int blk = blockIdx.x;           // 0..15
  const int t = blk >> 3, h = blk & 7;
  const int tid = threadIdx.x;
  const float* Asrc = (t ? Wv : Wq) + h * 4096;
  const float* Bsrc = (t ? Wp : Wk) + h * 4096;
  for (int i = tid; i < 4096; i += 256) {
    A[(i >> 6) * 65 + (i & 63)] = Asrc[i];
    B[(i >> 6) * 65 + (i & 63)] = Bsrc[i];
  }
  __syncthreads();
  unsigned short* dst = wf + blk * 4096;
  for (int o = 0; o < 16; ++o) {
    int idx = o * 256 + tid;
    int k = idx >> 6, n = idx & 63;
    float s = 0.f;
    if (t == 0) {
      for (int d = 0; d < 64; ++d) s += A[k * 65 + d] * B[n * 65 + d];
      s *= 0.18033688f;                 // 0.125 * log2(e)
    } else {
      for (int d = 0; d < 64; ++d) s += A[k * 65 + d] * B[d * 65 + n];
    }
    int kk = k >> 5, i = k & 7, lg = (k >> 3) & 3, si = n >> 4, l15 = n & 15;
    dst[((kk * 4 + si) * 64 + lg * 16 + l15) * 8 + i] = f2bf(s);
  }
}

// ---------------------------------------------------------------------------
// Main kernel: 256 threads = 4 waves; TWO WAVES PER BATCH, split by heads
// (hh=0: heads 0-3 + bias; hh=1: heads 4-7). Zero-barrier inner loop;
// partials combined via a 32 KB overlaid LDS block (R13 bug: the combine
// buffer (16 KB/batch) overran the 9 KB staging regions -> now explicitly
// disjoint: combine[bt] at bt*16 KB; staging only lives before barrier [2]).
// ---------------------------------------------------------------------------
__global__ __launch_bounds__(256, 4) void mha_fwd(
    const float* __restrict__ x, const unsigned short* __restrict__ wf,
    const float* __restrict__ bproj, float* __restrict__ out) {
  __shared__ __attribute__((aligned(16))) unsigned char smem[32768];
  unsigned short* XsBase = reinterpret_cast<unsigned short*>(smem);  // [2][64*LDA]

  const int tid  = threadIdx.x;
  const int lane = tid & 63;
  const int w    = tid >> 6;
  const int bt   = w & 1;            // batch within block
  const int hh   = w >> 1;           // head-half
  const int l15  = lane & 15;
  const int g    = lane >> 4;
  const int kcol = 8 * g;

  // ---- stage 2 batches (fp32 -> bf16, row-major [s][c]), coalesced ----
  const float* xb = x + (size_t)blockIdx.x * 8192;
  #pragma unroll
  for (int it = 0; it < 8; ++it) {
    int idx = it * 1024 + tid * 4;
    float4 v = *reinterpret_cast<const float4*>(xb + idx);
    f32x4 vv = {v.x, v.y, v.z, v.w};
    int sb = idx >> 12, rem = idx & 4095;
    *reinterpret_cast<u16x4*>(&XsBase[sb * (64 * LDA) + (rem >> 6) * LDA + (rem & 63)]) = pack4(vv);
  }
  __syncthreads();  // [1] X staged

  // ---- hoist this wave's X into registers (dual-role A/B frags) ----
  const unsigned short* Xmy = XsBase + bt * (64 * LDA);
  bf16x8 xf[2][4];   // element X[t*16+l15][cc*32 + 8g + i]
  #pragma unroll
  for (int cc = 0; cc < 2; ++cc)
    #pragma unroll
    for (int t = 0; t < 4; ++t)
      xf[cc][t] = frag8(&Xmy[(t * 16 + l15) * LDA + cc * 32 + kcol]);
  __syncthreads();  // [2] X reads done; smem reusable as combine buffer

  // ---- persistent out C-frags [mt][nt]; hh=0 carries the bias ----
  f32x4 oacc[4][4];
  #pragma unroll
  for (int nt = 0; nt < 4; ++nt) {
    float bias = hh ? 0.f : bproj[nt * 16 + l15];
    f32x4 bv = {bias, bias, bias, bias};
    #pragma unroll
    for (int mt = 0; mt < 4; ++mt) oacc[mt][nt] = bv;
  }

  const int h0 = hh * 4;
  for (int h = h0; h < h0 + 4; ++h) {
    const unsigned short* mf = wf + h * 4096;          // M^T A-frags
    const unsigned short* nf = wf + 32768 + h * 4096;  // N  B-frags

    bf16x8 Mf[2][4], Nf[2][4];
    #pragma unroll
    for (int kk = 0; kk < 2; ++kk)
      #pragma unroll
      for (int ct = 0; ct < 4; ++ct) {
        Mf[kk][ct] = frag8(&mf[(kk * 4 + ct) * 512 + lane * 8]);
        Nf[kk][ct] = frag8(&nf[(kk * 4 + ct) * 512 + lane * 8]);
      }

    // ---- G = M^T X^T, per output col-tile mt; immediate butterfly ----
    bf16x8 gB[2][4];
    #pragma unroll
    for (int mt = 0; mt < 4; ++mt) {
      f32x4 gc[4] = {};
      #pragma unroll
      for (int kk = 0; kk < 2; ++kk)
        #pragma unroll
        for (int ct = 0; ct < 4; ++ct)
          gc[ct] = MFMA(Mf[kk][ct], xf[kk][mt], gc[ct]);
      bf16x8 o2[2];
      cfrag2bfrag(gc, o2);
      gB[0][mt] = o2[0]; gB[1][mt] = o2[1];
    }

    // ---- S = X G with causal tile-skip; softmax; butterfly -> pA ----
    bf16x8 pA[2][4];
    #pragma unroll
    for (int mt = 0; mt < 4; ++mt) {
      f32x4 sc[4] = {};
      #pragma unroll
      for (int cc = 0; cc < 2; ++cc)
        #pragma unroll
        for (int st = 0; st < 4; ++st)
          if (st <= mt)
            sc[st] = MFMA(xf[cc][st], gB[cc][mt], sc[st]);
      const int m = mt * 16 + l15;
      float sum = 0.f;
      #pragma unroll
      for (int st = 0; st < 4; ++st) {
        if (st < mt) {
          #pragma unroll
          for (int r = 0; r < 4; ++r) { float e = exp2f(sc[st][r]); sc[st][r] = e; sum += e; }
        } else if (st == mt) {
          #pragma unroll
          for (int r = 0; r < 4; ++r) {
            int s = st * 16 + 4 * g + r;
            float e = (s <= m) ? exp2f(sc[st][r]) : 0.f;
            sc[st][r] = e; sum += e;
          }
        }
      }
      sum += __shfl_xor(sum, 16);
      sum += __shfl_xor(sum, 32);
      float rinv = __builtin_amdgcn_rcpf(sum);
      #pragma unroll
      for (int st = 0; st < 4; ++st)
        if (st <= mt) sc[st] *= rinv;
      bf16x8 o2[2];
      cfrag2bfrag(sc, o2);
      pA[0][mt] = o2[0]; pA[1][mt] = o2[1];
    }

    // ---- Z = X N, per col nt; butterfly -> zB ----
    bf16x8 zB[2][4];
    #pragma unroll
    for (int nt = 0; nt < 4; ++nt) {
      f32x4 zc[4] = {};
      #pragma unroll
      for (int st = 0; st < 4; ++st) {
        zc[st] = MFMA(xf[0][st], Nf[0][nt], zc[st]);
        zc[st] = MFMA(xf[1][st], Nf[1][nt], zc[st]);
      }
      bf16x8 o2[2];
      cfrag2bfrag(zc, o2);
      zB[0][nt] = o2[0]; zB[1][nt] = o2[1];
    }

    // ---- out += P Z ; causal k-range skip ----
    #pragma unroll
    for (int mt = 0; mt < 4; ++mt)
      #pragma unroll
      for (int nt = 0; nt < 4; ++nt) {
        oacc[mt][nt] = MFMA(pA[0][mt], zB[0][nt], oacc[mt][nt]);
        if (mt >= 2)
          oacc[mt][nt] = MFMA(pA[1][mt], zB[1][nt], oacc[mt][nt]);
      }
  }

  // ---- combine head-halves: disjoint 16 KB f32 regions per batch ----
  float* fbuf = reinterpret_cast<float*>(smem) + bt * 4096;  // bt*16 KB
  if (hh == 1) {
    #pragma unroll
    for (int mt = 0; mt < 4; ++mt)
      #pragma unroll
      for (int nt = 0; nt < 4; ++nt)
        *reinterpret_cast<f32x4*>(&fbuf[((mt * 4 + nt) * 64 + lane) * 4]) = oacc[mt][nt];
  }
  __syncthreads();  // [3] partials visible
  if (hh == 0) {
    float* ob = out + ((size_t)blockIdx.x * 2 + bt) * 4096;
    #pragma unroll
    for (int mt = 0; mt < 4; ++mt)
      #pragma unroll
      for (int r = 0; r < 4; ++r) {
        float* orow = ob + (mt * 16 + 4 * g + r) * 64;
        #pragma unroll
        for (int nt = 0; nt < 4; ++nt) {
          f32x4 other = *reinterpret_cast<const f32x4*>(&fbuf[((mt * 4 + nt) * 64 + lane) * 4]);
          orow[nt * 16 + l15] = oacc[mt][nt][r] + other[r];
        }
      }
  }
}

extern "C" void kernel_launch(void* const* d_in, const int* in_sizes, int n_in,
                              void* d_out, int out_size, void* d_ws, size_t ws_size,
                              hipStream_t stream) {
  const float* x  = (const float*)d_in[0];
  const float* Wq = (const float*)d_in[1];
  const float* Wk = (const float*)d_in[2];
  const float* Wv = (const float*)d_in[3];
  const float* Wp = (const float*)d_in[4];
  const float* bp = (const float*)d_in[5];
  unsigned short* wf = (unsigned short*)d_ws;  // 65536 bf16 = 128 KB fused-weight frags

  fuse_pack<<<dim3(16), dim3(256), 0, stream>>>(Wq, Wk, Wv, Wp, wf);
  mha_fwd<<<dim3(1024), dim3(256), 0, stream>>>(x, wf, bp, (float*)d_out);
}

// Round 16
// 59.429 us; speedup vs baseline: 2.1117x; 2.1117x over previous
//
#include <hip/hip_runtime.h>

typedef __bf16 bf16x8 __attribute__((ext_vector_type(8)));
typedef float f32x4 __attribute__((ext_vector_type(4)));
typedef unsigned short u16x4 __attribute__((ext_vector_type(4)));
typedef unsigned int u32x4 __attribute__((ext_vector_type(4)));

#define LDA 72    // bf16 row pitch (144 B): 16B-aligned rows

__device__ __forceinline__ unsigned short f2bf(float f) {
  __bf16 b = (__bf16)f;                      // hardware RTNE v_cvt
  return __builtin_bit_cast(unsigned short, b);
}

__device__ __forceinline__ u16x4 pack4(f32x4 v) {
  u16x4 r;
  r[0] = f2bf(v[0]); r[1] = f2bf(v[1]); r[2] = f2bf(v[2]); r[3] = f2bf(v[3]);
  return r;
}

__device__ __forceinline__ bf16x8 frag8(const unsigned short* p) {
  typedef unsigned short u16x8v __attribute__((ext_vector_type(8)));
  return __builtin_bit_cast(bf16x8, *reinterpret_cast<const u16x8v*>(p));
}

#define MFMA(a, b, c) __builtin_amdgcn_mfma_f32_16x16x32_bf16(a, b, c, 0, 0, 0)

// ---------------------------------------------------------------------------
// In-register C-frag -> A/B-frag conversion (validated permlane butterfly).
// ---------------------------------------------------------------------------
__device__ __forceinline__ void cfrag2bfrag(const f32x4 v[4], bf16x8 out[2]) {
  unsigned O[4][2];
  #pragma unroll
  for (int si = 0; si < 4; ++si) {
    u16x4 p = pack4(v[si]);
    O[si][0] = (unsigned)p[0] | ((unsigned)p[1] << 16);
    O[si][1] = (unsigned)p[2] | ((unsigned)p[3] << 16);
  }
  unsigned H[2][2][2];
  #pragma unroll
  for (int s1 = 0; s1 < 2; ++s1)
    #pragma unroll
    for (int d = 0; d < 2; ++d) {
      auto r = __builtin_amdgcn_permlane32_swap(O[2 * s1][d], O[2 * s1 + 1][d], false, false);
      H[s1][0][d] = r[0];
      H[s1][1][d] = r[1];
    }
  #pragma unroll
  for (int e1 = 0; e1 < 2; ++e1) {
    auto r0 = __builtin_amdgcn_permlane16_swap(H[e1][0][0], H[e1][1][0], false, false);
    auto r1 = __builtin_amdgcn_permlane16_swap(H[e1][0][1], H[e1][1][1], false, false);
    u32x4 f;
    f[0] = r0[0]; f[1] = r1[0]; f[2] = r0[1]; f[3] = r1[1];
    out[e1] = __builtin_bit_cast(bf16x8, f);
  }
}

// ---------------------------------------------------------------------------
// Fuse + pack (unchanged): t=0: M_h = Wq Wk^T * 0.125*log2e; t=1: N_h = Wv Wp_h.
// ---------------------------------------------------------------------------
__global__ __launch_bounds__(256) void fuse_pack(
    const float* __restrict__ Wq, const float* __restrict__ Wk,
    const float* __restrict__ Wv, const float* __restrict__ Wp,
    unsigned short* __restrict__ wf) {
  __shared__ float A[64 * 65];
  __shared__ float B[64 * 65];
  const int blk = blockIdx.x;           // 0..15
  const int t = blk >> 3, h = blk & 7;
  const int tid = threadIdx.x;
  const float* Asrc = (t ? Wv : Wq) + h * 4096;
  const float* Bsrc = (t ? Wp : Wk) + h * 4096;
  for (int i = tid; i < 4096; i += 256) {
    A[(i >> 6) * 65 + (i & 63)] = Asrc[i];
    B[(i >> 6) * 65 + (i & 63)] = Bsrc[i];
  }
  __syncthreads();
  unsigned short* dst = wf + blk * 4096;
  for (int o = 0; o < 16; ++o) {
    int idx = o * 256 + tid;
    int k = idx >> 6, n = idx & 63;
    float s = 0.f;
    if (t == 0) {
      for (int d = 0; d < 64; ++d) s += A[k * 65 + d] * B[n * 65 + d];
      s *= 0.18033688f;                 // 0.125 * log2(e)
    } else {
      for (int d = 0; d < 64; ++d) s += A[k * 65 + d] * B[d * 65 + n];
    }
    int kk = k >> 5, i = k & 7, lg = (k >> 3) & 3, si = n >> 4, l15 = n & 15;
    dst[((kk * 4 + si) * 64 + lg * 16 + l15) * 8 + i] = f2bf(s);
  }
}

// ---------------------------------------------------------------------------
// Main kernel: 256 threads = 4 waves; TWO WAVES PER BATCH, split by heads
// (hh=0: heads 0-3 + bias; hh=1: heads 4-7). Zero-barrier inner loop;
// partials combined via the 32 KB overlaid LDS block.
// launch_bounds(256,2): R14's (256,4) capped VGPR at 64 -> massive scratch
// spill (369 MB writes). At natural ~124 VGPR the HW still reaches 4
// waves/SIMD (16 waves/CU from the 4096-wave grid).
// ---------------------------------------------------------------------------
__global__ __launch_bounds__(256, 2) void mha_fwd(
    const float* __restrict__ x, const unsigned short* __restrict__ wf,
    const float* __restrict__ bproj, float* __restrict__ out) {
  __shared__ __attribute__((aligned(16))) unsigned char smem[32768];
  unsigned short* XsBase = reinterpret_cast<unsigned short*>(smem);  // [2][64*LDA]

  const int tid  = threadIdx.x;
  const int lane = tid & 63;
  const int w    = tid >> 6;
  const int bt   = w & 1;            // batch within block
  const int hh   = w >> 1;           // head-half
  const int l15  = lane & 15;
  const int g    = lane >> 4;
  const int kcol = 8 * g;

  // ---- stage 2 batches (fp32 -> bf16, row-major [s][c]), coalesced ----
  const float* xb = x + (size_t)blockIdx.x * 8192;
  #pragma unroll
  for (int it = 0; it < 8; ++it) {
    int idx = it * 1024 + tid * 4;
    float4 v = *reinterpret_cast<const float4*>(xb + idx);
    f32x4 vv = {v.x, v.y, v.z, v.w};
    int sb = idx >> 12, rem = idx & 4095;
    *reinterpret_cast<u16x4*>(&XsBase[sb * (64 * LDA) + (rem >> 6) * LDA + (rem & 63)]) = pack4(vv);
  }
  __syncthreads();  // [1] X staged

  // ---- hoist this wave's X into registers (dual-role A/B frags) ----
  const unsigned short* Xmy = XsBase + bt * (64 * LDA);
  bf16x8 xf[2][4];   // element X[t*16+l15][cc*32 + 8g + i]
  #pragma unroll
  for (int cc = 0; cc < 2; ++cc)
    #pragma unroll
    for (int t = 0; t < 4; ++t)
      xf[cc][t] = frag8(&Xmy[(t * 16 + l15) * LDA + cc * 32 + kcol]);
  __syncthreads();  // [2] X reads done; smem reusable as combine buffer

  // ---- persistent out C-frags [mt][nt]; hh=0 carries the bias ----
  f32x4 oacc[4][4];
  #pragma unroll
  for (int nt = 0; nt < 4; ++nt) {
    float bias = hh ? 0.f : bproj[nt * 16 + l15];
    f32x4 bv = {bias, bias, bias, bias};
    #pragma unroll
    for (int mt = 0; mt < 4; ++mt) oacc[mt][nt] = bv;
  }

  const int h0 = hh * 4;
  for (int h = h0; h < h0 + 4; ++h) {
    const unsigned short* mf = wf + h * 4096;          // M^T A-frags
    const unsigned short* nf = wf + 32768 + h * 4096;  // N  B-frags

    bf16x8 Mf[2][4], Nf[2][4];
    #pragma unroll
    for (int kk = 0; kk < 2; ++kk)
      #pragma unroll
      for (int ct = 0; ct < 4; ++ct) {
        Mf[kk][ct] = frag8(&mf[(kk * 4 + ct) * 512 + lane * 8]);
        Nf[kk][ct] = frag8(&nf[(kk * 4 + ct) * 512 + lane * 8]);
      }

    // ---- G = M^T X^T, per output col-tile mt; immediate butterfly ----
    bf16x8 gB[2][4];
    #pragma unroll
    for (int mt = 0; mt < 4; ++mt) {
      f32x4 gc[4] = {};
      #pragma unroll
      for (int kk = 0; kk < 2; ++kk)
        #pragma unroll
        for (int ct = 0; ct < 4; ++ct)
          gc[ct] = MFMA(Mf[kk][ct], xf[kk][mt], gc[ct]);
      bf16x8 o2[2];
      cfrag2bfrag(gc, o2);
      gB[0][mt] = o2[0]; gB[1][mt] = o2[1];
    }

    // ---- S = X G with causal tile-skip; softmax; butterfly -> pA ----
    bf16x8 pA[2][4];
    #pragma unroll
    for (int mt = 0; mt < 4; ++mt) {
      f32x4 sc[4] = {};
      #pragma unroll
      for (int cc = 0; cc < 2; ++cc)
        #pragma unroll
        for (int st = 0; st < 4; ++st)
          if (st <= mt)
            sc[st] = MFMA(xf[cc][st], gB[cc][mt], sc[st]);
      const int m = mt * 16 + l15;
      float sum = 0.f;
      #pragma unroll
      for (int st = 0; st < 4; ++st) {
        if (st < mt) {
          #pragma unroll
          for (int r = 0; r < 4; ++r) { float e = exp2f(sc[st][r]); sc[st][r] = e; sum += e; }
        } else if (st == mt) {
          #pragma unroll
          for (int r = 0; r < 4; ++r) {
            int s = st * 16 + 4 * g + r;
            float e = (s <= m) ? exp2f(sc[st][r]) : 0.f;
            sc[st][r] = e; sum += e;
          }
        }
      }
      sum += __shfl_xor(sum, 16);
      sum += __shfl_xor(sum, 32);
      float rinv = __builtin_amdgcn_rcpf(sum);
      #pragma unroll
      for (int st = 0; st < 4; ++st)
        if (st <= mt) sc[st] *= rinv;
      bf16x8 o2[2];
      cfrag2bfrag(sc, o2);
      pA[0][mt] = o2[0]; pA[1][mt] = o2[1];
    }

    // ---- Z = X N, per col nt; butterfly -> zB ----
    bf16x8 zB[2][4];
    #pragma unroll
    for (int nt = 0; nt < 4; ++nt) {
      f32x4 zc[4] = {};
      #pragma unroll
      for (int st = 0; st < 4; ++st) {
        zc[st] = MFMA(xf[0][st], Nf[0][nt], zc[st]);
        zc[st] = MFMA(xf[1][st], Nf[1][nt], zc[st]);
      }
      bf16x8 o2[2];
      cfrag2bfrag(zc, o2);
      zB[0][nt] = o2[0]; zB[1][nt] = o2[1];
    }

    // ---- out += P Z ; causal k-range skip ----
    #pragma unroll
    for (int mt = 0; mt < 4; ++mt)
      #pragma unroll
      for (int nt = 0; nt < 4; ++nt) {
        oacc[mt][nt] = MFMA(pA[0][mt], zB[0][nt], oacc[mt][nt]);
        if (mt >= 2)
          oacc[mt][nt] = MFMA(pA[1][mt], zB[1][nt], oacc[mt][nt]);
      }
  }

  // ---- combine head-halves: disjoint 16 KB f32 regions per batch ----
  float* fbuf = reinterpret_cast<float*>(smem) + bt * 4096;  // bt*16 KB
  if (hh == 1) {
    #pragma unroll
    for (int mt = 0; mt < 4; ++mt)
      #pragma unroll
      for (int nt = 0; nt < 4; ++nt)
        *reinterpret_cast<f32x4*>(&fbuf[((mt * 4 + nt) * 64 + lane) * 4]) = oacc[mt][nt];
  }
  __syncthreads();  // [3] partials visible
  if (hh == 0) {
    float* ob = out + ((size_t)blockIdx.x * 2 + bt) * 4096;
    #pragma unroll
    for (int mt = 0; mt < 4; ++mt)
      #pragma unroll
      for (int r = 0; r < 4; ++r) {
        float* orow = ob + (mt * 16 + 4 * g + r) * 64;
        #pragma unroll
        for (int nt = 0; nt < 4; ++nt) {
          f32x4 other = *reinterpret_cast<const f32x4*>(&fbuf[((mt * 4 + nt) * 64 + lane) * 4]);
          orow[nt * 16 + l15] = oacc[mt][nt][r] + other[r];
        }
      }
  }
}

extern "C" void kernel_launch(void* const* d_in, const int* in_sizes, int n_in,
                              void* d_out, int out_size, void* d_ws, size_t ws_size,
                              hipStream_t stream) {
  const float* x  = (const float*)d_in[0];
  const float* Wq = (const float*)d_in[1];
  const float* Wk = (const float*)d_in[2];
  const float* Wv = (const float*)d_in[3];
  const float* Wp = (const float*)d_in[4];
  const float* bp = (const float*)d_in[5];
  unsigned short* wf = (unsigned short*)d_ws;  // 65536 bf16 = 128 KB fused-weight frags

  fuse_pack<<<dim3(16), dim3(256), 0, stream>>>(Wq, Wk, Wv, Wp, wf);
  mha_fwd<<<dim3(1024), dim3(256), 0, stream>>>(x, wf, bp, (float*)d_out);
}